// Round 16
// baseline (98.364 us; speedup 1.0000x reference)
//
#include <hip/hip_runtime.h>
#include <hip/hip_bf16.h>

// GCN forward v8: out = PReLU(adj @ (seq @ W^T) + bias)
// B=256, N=512, F=64. TLP experiment: pipelining x block-independence.
//  fc  (R1-verified): sftT = (seq@W^T)^T bf16 [b][o][tok] -> d_ws (16 MB).
//  agg: 2048 independent blocks (4 waves, 16 KB LDS) -> 4 blocks/CU,
//    16 waves/CU free-running. Each block: 64 adj rows as 16 pipelined
//    [16 rows x 128 k] chunks (double-buffered global_load_lds, counted
//    vmcnt, in-order-retirement audited), bbr register-cached from L2-hot
//    sftT (XCD-chunked swizzle). Bodies fully unrolled (static bbr indices).

#define BATCH 256
#define NTOK  512
#define INF   64
#define OUTF  64

typedef __attribute__((ext_vector_type(8))) __bf16 bf16x8;
typedef __attribute__((ext_vector_type(4))) __bf16 bf16x4;
typedef __attribute__((ext_vector_type(4))) float  f32x4;

typedef const __attribute__((address_space(1))) char GChar;
typedef __attribute__((address_space(3))) char LChar;

__device__ __forceinline__ bf16x8 load_cvt8(const float* __restrict__ p) {
    float4 lo = *(const float4*)p;
    float4 hi = *(const float4*)(p + 4);
    bf16x8 r;
    r[0] = (__bf16)lo.x; r[1] = (__bf16)lo.y; r[2] = (__bf16)lo.z; r[3] = (__bf16)lo.w;
    r[4] = (__bf16)hi.x; r[5] = (__bf16)hi.y; r[6] = (__bf16)hi.z; r[7] = (__bf16)hi.w;
    return r;
}

__device__ __forceinline__ bf16x8 pack8(float4 lo, float4 hi) {
    bf16x8 r;
    r[0] = (__bf16)lo.x; r[1] = (__bf16)lo.y; r[2] = (__bf16)lo.z; r[3] = (__bf16)lo.w;
    r[4] = (__bf16)hi.x; r[5] = (__bf16)hi.y; r[6] = (__bf16)hi.z; r[7] = (__bf16)hi.w;
    return r;
}

// ---------------- Kernel A: seq_fts^T = (seq @ W^T)^T -> bf16 (R1, verified)
__global__ __launch_bounds__(256) void GCN_fc_kernel(
        const float* __restrict__ seq, const float* __restrict__ W,
        __bf16* __restrict__ sftT) {
    int blk  = blockIdx.x;
    int b    = blk >> 3;
    int m0   = (blk & 7) * 64;
    int tid  = threadIdx.x;
    int wave = tid >> 6;
    int lane = tid & 63;
    int row16 = lane & 15;
    int g     = lane >> 4;
    int mbase = m0 + wave * 16;

    const float* sp = seq + ((size_t)b * NTOK + (mbase + row16)) * INF + g * 8;
    const float* wp = W + (size_t)row16 * INF + g * 8;

    f32x4 acc[4] = {};
#pragma unroll
    for (int ks = 0; ks < 2; ++ks) {
        bf16x8 a = load_cvt8(sp + ks * 32);
#pragma unroll
        for (int nt = 0; nt < 4; ++nt) {
            bf16x8 w8 = load_cvt8(wp + (size_t)nt * 16 * INF + ks * 32);
            acc[nt] = __builtin_amdgcn_mfma_f32_16x16x32_bf16(a, w8, acc[nt], 0, 0, 0);
        }
    }
#pragma unroll
    for (int nt = 0; nt < 4; ++nt) {
        int o = nt * 16 + row16;
        bf16x4 v;
        v[0] = (__bf16)acc[nt][0]; v[1] = (__bf16)acc[nt][1];
        v[2] = (__bf16)acc[nt][2]; v[3] = (__bf16)acc[nt][3];
        __bf16* dst = sftT + ((size_t)b * OUTF + o) * NTOK + mbase + g * 4;
        *(bf16x4*)dst = v;
    }
}

// ---------------- Kernel B: out = PReLU(adj @ seq_fts + bias) ----------------
// grid = 2048 (256 batches x 8 row-blocks of 64), block = 256 (4 waves),
// LDS 16 KB (2 x [16 rows x 128 k] fp32). Wave c4 owns cols [c4*16, +16),
// bbr = 16 bf16x8 (full K) from sftT. 16 bodies: rg 0..3 x kq 0..3.
__global__ __launch_bounds__(256, 4) void GCN_agg_kernel(
        const float* __restrict__ adj, const __bf16* __restrict__ sftT,
        const float* __restrict__ bias, const float* __restrict__ alpha_p,
        float* __restrict__ out) {
    __shared__ float smem[4096];             // 16 KB
    float* buf0 = smem;                      // [16][128] fp32
    float* buf1 = smem + 2048;

    // XCD-chunked: 2048 = 8 x 256; a batch's 8 blocks share one XCD's L2.
    int p = blockIdx.x;
    int logical = (p & 7) * 256 + (p >> 3);  // bijective
    int b  = logical >> 3;
    int r0 = (logical & 7) * 64;             // this block's 64 adj rows

    int tid  = threadIdx.x;
    int wave = tid >> 6;                     // 0..3 = col-group c4
    int lane = tid & 63;
    int row16 = lane & 15;
    int g     = lane >> 4;                   // 0..3
    int rs    = row16 & 7;

    const float* gadj = adj + ((size_t)b * NTOK + r0) * NTOK;

    // STAGE chunk CH = rg*4+kq (rows [rg*16,+16), k [kq*128,+128)): 8 x 1-KB
    // global_load_lds, 2 per wave. Load idx covers rows 2idx, 2idx+1; lane:
    // rl = 2idx+(lane>>5), fetches swizzled 16-B slot (lane&31)^(rl&7) so
    // linear LDS holds LDS[r][s] = G[r][kq*128 + 4*(s ^ (r&7))].
#define STAGE(dstf, CH) do {                                                   \
    _Pragma("unroll")                                                          \
    for (int i_ = 0; i_ < 2; ++i_) {                                           \
        int idx_ = wave * 2 + i_;                                              \
        int rl_  = 2 * idx_ + (lane >> 5);                                     \
        int sl_  = (lane & 31) ^ (rl_ & 7);                                    \
        __builtin_amdgcn_global_load_lds(                                      \
            (GChar*)(gadj + (size_t)(((CH) >> 2) * 16 + rl_) * NTOK            \
                     + ((CH) & 3) * 128 + sl_ * 4),                            \
            (LChar*)((dstf) + idx_ * 256), 16, 0, 0);                          \
    }                                                                          \
} while (0)

    STAGE(buf0, 0);                          // chunk 0 first (oldest in vmcnt)

    // B-frags: this wave's 16 cols, full K (64 VGPR), from L2-hot sftT.
    int o = wave * 16 + row16;
    const __bf16* brow = sftT + ((size_t)b * OUTF + o) * NTOK + g * 8;
    bf16x8 bbr[16];
#pragma unroll
    for (int t = 0; t < 16; ++t)
        bbr[t] = *(const bf16x8*)(brow + t * 32);

    float bv     = bias[o];
    float alphav = alpha_p[0];
    f32x4 acc;
    acc[0] = bv; acc[1] = bv; acc[2] = bv; acc[3] = bv;

    // 16 bodies, fully unrolled (compile-time i: bbr index + vmcnt counts).
    // vmcnt audit (in-order retirement; counts = ops newer than G(i)):
    //   i==0: bbr(16)+G0(2) drained by waiting newer(G1)=2 -> vmcnt(2)
    //   i%4==0,i>0: stores(4)+G(i+1)(2) -> vmcnt(6)
    //   i==15: no stage -> vmcnt(0);  else -> vmcnt(2)
#pragma unroll
    for (int i = 0; i < 16; ++i) {
        float* cur = (i & 1) ? buf1 : buf0;
        float* nxt = (i & 1) ? buf0 : buf1;

        if (i > 0) {                         // all waves done reading nxt's old chunk
            __builtin_amdgcn_sched_barrier(0);
            __builtin_amdgcn_s_barrier();
            __builtin_amdgcn_sched_barrier(0);
        }
        if (i < 15) STAGE(nxt, i + 1);
        __builtin_amdgcn_sched_barrier(0);
        if (i == 0)            asm volatile("s_waitcnt vmcnt(2)" ::: "memory");
        else if (i == 15)      asm volatile("s_waitcnt vmcnt(0)" ::: "memory");
        else if ((i & 3) == 0) asm volatile("s_waitcnt vmcnt(6)" ::: "memory");
        else                   asm volatile("s_waitcnt vmcnt(2)" ::: "memory");
        __builtin_amdgcn_sched_barrier(0);
        __builtin_amdgcn_s_barrier();        // chunk i landed for all 4 waves
        __builtin_amdgcn_sched_barrier(0);

        // compute: 16 rows x this wave's 16 cols, k-quarter i&3 (4 MFMAs)
#pragma unroll
        for (int tt = 0; tt < 4; ++tt) {
            int s0 = (tt * 8 + g * 2) ^ rs;
            float4 f0 = *(const float4*)(cur + row16 * 128 + s0 * 4);
            float4 f1 = *(const float4*)(cur + row16 * 128 + (s0 ^ 1) * 4);
            bf16x8 a = pack8(f0, f1);
            acc = __builtin_amdgcn_mfma_f32_16x16x32_bf16(a, bbr[(i & 3) * 4 + tt], acc, 0, 0, 0);
        }

        if ((i & 3) == 3) {                  // row-group complete: PReLU + store
            int m = r0 + (i >> 2) * 16 + g * 4;
            float* op = out + ((size_t)b * NTOK + m) * OUTF + o;
#pragma unroll
            for (int j = 0; j < 4; ++j) {    // C/D row = g*4 + j
                float v = acc[j];
                op[(size_t)j * OUTF] = (v >= 0.f) ? v : alphav * v;
            }
            acc[0] = bv; acc[1] = bv; acc[2] = bv; acc[3] = bv;
        }
    }
#undef STAGE
}

extern "C" void kernel_launch(void* const* d_in, const int* in_sizes, int n_in,
                              void* d_out, int out_size, void* d_ws, size_t ws_size,
                              hipStream_t stream) {
    const float* seq   = (const float*)d_in[0];
    const float* adj   = (const float*)d_in[1];
    const float* W     = (const float*)d_in[2];
    const float* bias  = (const float*)d_in[3];
    const float* alpha = (const float*)d_in[4];
    float* out = (float*)d_out;
    __bf16* sftT = (__bf16*)d_ws;            // 256*64*512*2 = 16 MB scratch

    GCN_fc_kernel<<<dim3(2048), dim3(256), 0, stream>>>(seq, W, sftT);
    GCN_agg_kernel<<<dim3(2048), dim3(256), 0, stream>>>(adj, sftT, bias, alpha, out);
}

// Round 17
// 69.503 us; speedup vs baseline: 1.4152x; 1.4152x over previous
//
#include <hip/hip_runtime.h>
#include <hip/hip_bf16.h>

// GCN forward FUSED v9: out = PReLU(adj @ (seq @ W^T) + bias)
// B=256, N=512, F=64. grid=256 (1 block/batch/CU), block=512 (8 waves), 128KB LDS.
// Refinement of R15 (68.7us): 4-buffer rotation of [64 rows x 128 k] 32-KB
// chunks -> ONE s_barrier per body (was 3) and prefetch depth 2 (G(i+2)
// issued 2 bodies ahead). Hazard: buf[(i+2)%4] last read in compute(i-2),
// complete before barrier(i) for all waves -> single barrier suffices.
// vmcnt audit (stores count in vmcnt): i==0 ->4, i%4==0 ->8, else ->4, last ->0.
// Buffers 2,3 overlay sft (dead after redistribute); raw lgkmcnt-only barriers
// keep prologue stages in flight. Phase 1 / redistribute / full-line
// ds_bpermute store retile = R15 verbatim.

#define BATCH 256
#define NTOK  512
#define INF   64
#define OUTF  64

typedef __attribute__((ext_vector_type(8))) __bf16 bf16x8;
typedef __attribute__((ext_vector_type(4))) __bf16 bf16x4;
typedef __attribute__((ext_vector_type(4))) float  f32x4;

typedef const __attribute__((address_space(1))) char GChar;
typedef __attribute__((address_space(3))) char LChar;

__device__ __forceinline__ bf16x8 load_cvt8(const float* __restrict__ p) {
    float4 lo = *(const float4*)p;
    float4 hi = *(const float4*)(p + 4);
    bf16x8 r;
    r[0] = (__bf16)lo.x; r[1] = (__bf16)lo.y; r[2] = (__bf16)lo.z; r[3] = (__bf16)lo.w;
    r[4] = (__bf16)hi.x; r[5] = (__bf16)hi.y; r[6] = (__bf16)hi.z; r[7] = (__bf16)hi.w;
    return r;
}

__device__ __forceinline__ bf16x8 pack8(float4 lo, float4 hi) {
    bf16x8 r;
    r[0] = (__bf16)lo.x; r[1] = (__bf16)lo.y; r[2] = (__bf16)lo.z; r[3] = (__bf16)lo.w;
    r[4] = (__bf16)hi.x; r[5] = (__bf16)hi.y; r[6] = (__bf16)hi.z; r[7] = (__bf16)hi.w;
    return r;
}

__global__ __launch_bounds__(512) void GCN_fused_kernel(
        const float* __restrict__ seq, const float* __restrict__ adj,
        const float* __restrict__ W, const float* __restrict__ bias,
        const float* __restrict__ alpha_p, float* __restrict__ out) {
    __shared__ float smem[32768];            // 128 KB

    int b    = blockIdx.x;
    int tid  = threadIdx.x;
    int wave = tid >> 6;                     // 0..7
    int lane = tid & 63;
    int row16 = lane & 15;
    int g     = lane >> 4;                   // 0..3
    int mt    = wave >> 1;                   // 0..3: rows [mt*16,+16) of 64-row chunk
    int c2    = wave & 1;                    // 0/1:  cols [c2*32,+32)
    int rs    = row16 & 7;

    __bf16* sft  = (__bf16*)smem;            // [64 o][512 k] bf16 (lower 64 KB)
    float* bufp2 = smem;                     // overlays sft rows 0..31
    float* bufp3 = smem + 8192;              // overlays sft rows 32..63
    float* bufp0 = smem + 16384;             // fresh upper 64 KB
    float* bufp1 = smem + 24576;

    const float* gadj = adj + (size_t)b * NTOK * NTOK;

    // STAGE chunk CH = rg*4+kq (rows [rg*64,+64), k [kq*128,+128)): 32 KB =
    // 32 x 1-KB global_load_lds, 4/wave. Load idx covers rows 2idx,2idx+1;
    // lane: rl = 2idx+(lane>>5), fetches swizzled 16-B slot (lane&31)^(rl&7)
    // so linear LDS holds LDS[r][s] = G[r][kq*128 + 4*(s ^ (r&7))].
#define STAGE(dstf, CH) do {                                                   \
    _Pragma("unroll")                                                          \
    for (int i_ = 0; i_ < 4; ++i_) {                                           \
        int idx_ = wave * 4 + i_;                                              \
        int rl_  = 2 * idx_ + (lane >> 5);                                     \
        int sl_  = (lane & 31) ^ (rl_ & 7);                                    \
        __builtin_amdgcn_global_load_lds(                                      \
            (GChar*)(gadj + (size_t)(((CH) >> 2) * 64 + rl_) * NTOK            \
                     + ((CH) & 3) * 128 + sl_ * 4),                            \
            (LChar*)((dstf) + idx_ * 256), 16, 0, 0);                          \
    }                                                                          \
} while (0)

    // bias/alpha first (their auto-wait then can't drain the stages below)
    float bv2[2];
#pragma unroll
    for (int ti = 0; ti < 2; ++ti) bv2[ti] = bias[c2 * 32 + ti * 16 + row16];
    float alphav = alpha_p[0];

    STAGE(bufp0, 0);                         // chunks 0,1 in flight under phase 1
    STAGE(bufp1, 1);
    __builtin_amdgcn_sched_barrier(0);

    // ================= Phase 1: sft[o][k] = (seq @ W^T)^T ===================
    {
        int mb = wave * 64;
        bf16x8 wf[4][2];
#pragma unroll
        for (int nt = 0; nt < 4; ++nt)
#pragma unroll
            for (int ks = 0; ks < 2; ++ks)
                wf[nt][ks] = load_cvt8(W + (size_t)(nt * 16 + row16) * INF + ks * 32 + g * 8);

#pragma unroll
        for (int mt2 = 0; mt2 < 4; ++mt2) {
            f32x4 pa[4] = {};
#pragma unroll
            for (int ks = 0; ks < 2; ++ks) {
                bf16x8 af = load_cvt8(seq + ((size_t)b * NTOK + mb + mt2 * 16 + row16) * INF + ks * 32 + g * 8);
#pragma unroll
                for (int nt = 0; nt < 4; ++nt)
                    pa[nt] = __builtin_amdgcn_mfma_f32_16x16x32_bf16(af, wf[nt][ks], pa[nt], 0, 0, 0);
            }
            // D: col(o)=row16-part, row(tok)=g*4+reg. Swizzled store:
            // 16-B slot s = k>>3 stored at s ^ (o&7), within-slot offset k&7.
#pragma unroll
            for (int nt = 0; nt < 4; ++nt) {
                int o    = nt * 16 + row16;
                int ktok = mb + mt2 * 16 + g * 4;
                int sw   = (ktok >> 3) ^ (o & 7);
                bf16x4 v;
                v[0] = (__bf16)pa[nt][0]; v[1] = (__bf16)pa[nt][1];
                v[2] = (__bf16)pa[nt][2]; v[3] = (__bf16)pa[nt][3];
                *(bf16x4*)((char*)sft + (size_t)o * 1024 + sw * 16 + (ktok & 7) * 2) = v;
            }
        }
    }
    // raw barrier (LDS-only drain): sft visible, stages stay in flight
    asm volatile("s_waitcnt lgkmcnt(0)" ::: "memory");
    __builtin_amdgcn_sched_barrier(0);
    __builtin_amdgcn_s_barrier();
    __builtin_amdgcn_sched_barrier(0);

    // ==== Redistribute: B-frags for this wave's 32 cols, ALL K (128 VGPR) ===
    bf16x8 bbr2[16][2];
#pragma unroll
    for (int t = 0; t < 16; ++t)
#pragma unroll
        for (int ti = 0; ti < 2; ++ti) {
            int o  = c2 * 32 + ti * 16 + row16;
            int sw = ((t << 2) + g) ^ rs;
            bbr2[t][ti] = *(const bf16x8*)((const char*)sft + (size_t)o * 1024 + sw * 16);
        }
    // raw barrier: all waves done reading sft -> bufp2/3 reusable
    asm volatile("s_waitcnt lgkmcnt(0)" ::: "memory");
    __builtin_amdgcn_sched_barrier(0);
    __builtin_amdgcn_s_barrier();
    __builtin_amdgcn_sched_barrier(0);

    // ================= Phase 2: 32 bodies (rg 0..7 x kq 0..3) ===============
    f32x4 acc2[2];
#pragma unroll
    for (int ti = 0; ti < 2; ++ti) {
        acc2[ti][0] = bv2[ti]; acc2[ti][1] = bv2[ti];
        acc2[ti][2] = bv2[ti]; acc2[ti][3] = bv2[ti];
    }

#pragma unroll 1
    for (int rg = 0; rg < 8; ++rg) {
#pragma unroll
        for (int kq = 0; kq < 4; ++kq) {     // body i = rg*4+kq; buf = kq
            float* cur = (kq == 0) ? bufp0 : (kq == 1) ? bufp1
                       : (kq == 2) ? bufp2 : bufp3;
            float* nxt = (kq == 0) ? bufp2 : (kq == 1) ? bufp3
                       : (kq == 2) ? bufp0 : bufp1;   // buf (kq+2)%4

            // drain G(i): newer = G(i+1) [+ stores if kq==0 && rg>0]
            if (rg == 0 && kq == 0)      asm volatile("s_waitcnt vmcnt(4)" ::: "memory");
            else if (rg == 7 && kq == 3) asm volatile("s_waitcnt vmcnt(0)" ::: "memory");
            else if (kq == 0)            asm volatile("s_waitcnt vmcnt(8)" ::: "memory");
            else                         asm volatile("s_waitcnt vmcnt(4)" ::: "memory");
            __builtin_amdgcn_sched_barrier(0);
            __builtin_amdgcn_s_barrier();    // chunk i landed for ALL waves
            __builtin_amdgcn_sched_barrier(0);
            // prefetch chunk i+2 into buf (kq+2)%4 (read at i-2, safe past barrier i)
            if (!(rg == 7 && kq >= 2)) STAGE(nxt, rg * 4 + kq + 2);
            __builtin_amdgcn_sched_barrier(0);

            // compute: 16 rows x 32 cols, k-quarter kq (4 ksteps x 2 col-frags)
            {
                int rowb_ = (mt * 16 + row16) * 128;
#pragma unroll
                for (int tt = 0; tt < 4; ++tt) {
                    int s0 = (tt * 8 + g * 2) ^ rs;
                    float4 f0 = *(const float4*)(cur + rowb_ + s0 * 4);
                    float4 f1 = *(const float4*)(cur + rowb_ + (s0 ^ 1) * 4);
                    bf16x8 a = pack8(f0, f1);
                    acc2[0] = __builtin_amdgcn_mfma_f32_16x16x32_bf16(a, bbr2[kq * 4 + tt][0], acc2[0], 0, 0, 0);
                    acc2[1] = __builtin_amdgcn_mfma_f32_16x16x32_bf16(a, bbr2[kq * 4 + tt][1], acc2[1], 0, 0, 0);
                }
            }

            if (kq == 3) {
                // finalize row-group: PReLU + in-wave retile + full-line store
                float p0[4], p1[4];
#pragma unroll
                for (int j = 0; j < 4; ++j) {
                    float v0 = acc2[0][j]; p0[j] = (v0 >= 0.f) ? v0 : alphav * v0;
                    float v1 = acc2[1][j]; p1[j] = (v1 >= 0.f) ? v1 : alphav * v1;
                }
                int addrA = (g * 16 + ((2 * row16) & 15)) << 2;
                int addrB = (g * 16 + ((2 * row16 + 1) & 15)) << 2;
                bool loSel = (row16 < 8);    // cols < 16 come from acc2[0]
#pragma unroll
                for (int j = 0; j < 4; ++j) {
                    int a0 = __builtin_amdgcn_ds_bpermute(addrA, __float_as_int(p0[j]));
                    int a1 = __builtin_amdgcn_ds_bpermute(addrA, __float_as_int(p1[j]));
                    int b0 = __builtin_amdgcn_ds_bpermute(addrB, __float_as_int(p0[j]));
                    int b1 = __builtin_amdgcn_ds_bpermute(addrB, __float_as_int(p1[j]));
                    float lo = __int_as_float(loSel ? a0 : a1);
                    float hi = __int_as_float(loSel ? b0 : b1);
                    float2 st = make_float2(lo, hi);
                    *(float2*)(out + ((size_t)b * NTOK + rg * 64 + mt * 16 + g * 4 + j) * OUTF
                               + c2 * 32 + 2 * row16) = st;
                    acc2[0][j] = bv2[0];     // re-init for next row-group
                    acc2[1][j] = bv2[1];
                }
            }
        }
    }
#undef STAGE
}

extern "C" void kernel_launch(void* const* d_in, const int* in_sizes, int n_in,
                              void* d_out, int out_size, void* d_ws, size_t ws_size,
                              hipStream_t stream) {
    const float* seq   = (const float*)d_in[0];
    const float* adj   = (const float*)d_in[1];
    const float* W     = (const float*)d_in[2];
    const float* bias  = (const float*)d_in[3];
    const float* alpha = (const float*)d_in[4];
    float* out = (float*)d_out;

    GCN_fused_kernel<<<dim3(BATCH), dim3(512), 0, stream>>>(seq, adj, W, bias, alpha, out);
}